// Round 19
// baseline (431.487 us; speedup 1.0000x reference)
//
#include <hip/hip_runtime.h>

// Problem constants (B,T,C,F fixed by harness)
constexpr int BB = 8;
constexpr int TT = 512;
constexpr int CHN = 8;
constexpr int FF = 257;
constexpr int TAPS = 5;
constexpr int DELAY = 3;
constexpr int NBF = BB * FF;          // 2056 independent (b,f) systems
constexpr int ROWQ = 20;              // k_tail LDS floats per t-row
constexpr int MC = 48;                // augmented matrix cols (40 R + 8 rhs)
constexpr int RS = 98;                // solver LDS row stride in floats (48*2 + 2 pad)
constexpr int PSTR = 264;             // k_corr panel plane stride (EVEN: aligned b64 pairs)
constexpr int TROWS = 263;            // k_tail chunked panel rows (256 + 7 halo)

typedef short s8v __attribute__((ext_vector_type(8)));   // bf16x8 MFMA fragment
typedef float f4  __attribute__((ext_vector_type(4)));   // f32x4 accumulator
typedef float v2f __attribute__((ext_vector_type(2)));   // packed f32 pair
#define FMA2(a, b, c) __builtin_elementwise_fma((a), (b), (c))

// ---------------------------------------------------------------------------
// K1: (B,T,C,F) re/im -> Yg[b][f][t][c][2]  (time-contiguous complex layout)
// Also emits power[b][f][t] = mean_c |Y|^2 from the staged tile (fused power0).
// ---------------------------------------------------------------------------
__global__ void k_pack(const float* __restrict__ re, const float* __restrict__ im,
                       float* __restrict__ Yg, float* __restrict__ pw) {
  const int ft = blockIdx.x, tt = blockIdx.y, b = blockIdx.z;
  const int f0 = ft * 32, t0 = tt * 16;
  __shared__ float ls[32 * 258];
  const int tid = threadIdx.x;
  const int l = tid & 31;   // f lane
  const int r = tid >> 5;   // 0..7
  const int f = f0 + l;
  if (f < FF) {
    for (int k = 0; k < 32; ++k) {
      const int task = r + 8 * k;       // 0..255 -> (t,c,ri)
      const int ri = task & 1;
      const int c  = (task >> 1) & 7;
      const int t  = task >> 4;         // 0..15
      const float* src = ri ? im : re;
      const float v = src[(((size_t)b * TT + t0 + t) * CHN + c) * FF + f];
      ls[l * 258 + (t * 16 + c * 2 + ri)] = v;
    }
  }
  __syncthreads();
  for (int ff = 0; ff < 32; ++ff) {
    const int fg = f0 + ff;
    if (fg >= FF) break;
    Yg[(((size_t)b * FF + fg) * TT + t0) * 16 + tid] = ls[ff * 258 + tid];
  }
  // fused initial power: thread (l, r) handles (f=f0+l, t = r, r+8)
  if (f < FF) {
#pragma unroll
    for (int s = 0; s < 2; ++s) {
      const int t = (tid >> 5) + 8 * s;
      const float* row = &ls[l * 258 + t * 16];
      float ss = 0.f;
#pragma unroll
      for (int q = 0; q < 8; ++q) {
        const float2 v = *(const float2*)&row[q * 2];
        ss += v.x * v.x + v.y * v.y;
      }
      pw[((size_t)b * FF + f) * TT + t0 + t] = ss * (1.0f / CHN);
    }
  }
}

// ---------------------------------------------------------------------------
// round-to-nearest f32 -> bf16 bit pattern
// ---------------------------------------------------------------------------
__device__ __forceinline__ unsigned bf16rn(float x) {
  unsigned b = __float_as_uint(x);
  return (b + 0x7fffu + ((b >> 16) & 1u)) >> 16;
}

// ---------------------------------------------------------------------------
// K3 (round-19): chunked bf16-MFMA corr with CHANNEL-PLANAR panel.
// Per (b,f) accumulate M = [R | b] (40x48 complex), M = C^H C (sqrt-weight
// u[t]=rsqrt(max(p,eps)), 0 for t<7), Hermitian mirror, 6 upper-tri waves,
// hi/lo bf16 split (3 MFMA/real product), 2 barriers/K-tile.
// LDS-traffic cut (r18 analysis: build's 6 scalar ds_read_b32/cell make the
// kernel LDS-pipe bound): panel stored as 16 planes panel[plane][t] (stride
// 264, even) + flat ul[256], so:
//   - (u0,u1) is ONE aligned b64 (t even)        [all rows]
//   - (s0,s1) pre/pim pairs are ONE b64 each when sh even (rows q1,q3,direct)
//   -> avg 4 reads/cell vs 6, pair reads lane-contiguous (conflict-free).
// sh-parity is uniform per wave (wave = 4 rows within one 8-row tap block).
// ch1 panel base r0=248 (even) keeps locals aligned. LDS 33.3 KB, 4 blk/CU.
// ---------------------------------------------------------------------------
__global__ __launch_bounds__(384, 4)
void k_corr(const float* __restrict__ Yg,
            const float* __restrict__ pw,
            float2* __restrict__ Mg) {
  const int bf = blockIdx.x;
  __shared__ float panel[16 * PSTR];             // planes 0-7: re[e], 8-15: im[e]
  __shared__ float ul[256];                      // u[t] for current chunk
  __shared__ unsigned short tiles[4 * 1920];     // CRH | CRL | CIH | CIL, 48x40
  const int tid = threadIdx.x;

  const int lane = tid & 63, wv = tid >> 6;      // 6 waves
  const int rt = (wv < 3) ? 0 : (wv < 5 ? 1 : 2);
  const int ct = (wv < 3) ? wv : (wv < 5 ? wv - 2 : 2);
  const int lr = lane & 15, lk = lane >> 4;
  const int aoff = (rt * 16 + lr) * 40 + lk * 8;
  const int boff = (ct * 16 + lr) * 40 + lk * 8;

  f4 accre  = {0.f, 0.f, 0.f, 0.f};
  f4 accim1 = {0.f, 0.f, 0.f, 0.f};
  f4 accim2 = {0.f, 0.f, 0.f, 0.f};

  const float4* ybase4 = (const float4*)(Yg + (size_t)bf * TT * 16);

  for (int ch = 0; ch < 2; ++ch) {
    const int t0c = ch * 256;
    const int r0  = (ch == 0) ? 0 : 248;         // EVEN panel base (halo 248..255)
    const int nr  = (ch == 0) ? 256 : 264;       // plane rows staged
    // ---- stage: global float4 -> 4 planar scalars ----
    for (int fi = tid; fi < nr * 4; fi += 384) {
      const int row = fi >> 2, q = fi & 3;       // q = complex pair index
      const float4 v = ybase4[(size_t)(r0 + row) * 4 + q];
      panel[(2 * q)     * PSTR + row] = v.x;     // re[2q]
      panel[(8 + 2 * q) * PSTR + row] = v.y;     // im[2q]
      panel[(2 * q + 1) * PSTR + row] = v.z;     // re[2q+1]
      panel[(9 + 2 * q) * PSTR + row] = v.w;     // im[2q+1]
    }
    for (int t = t0c + tid; t < t0c + 256; t += 384) {
      const float p = pw[(size_t)bf * TT + t];
      ul[t - t0c] = (t >= DELAY + TAPS - 1) ? rsqrtf(fmaxf(p, 1e-10f)) : 0.0f;
    }
    __syncthreads();                             // panel chunk ready

    for (int ktl = 0; ktl < 8; ++ktl) {
      const int kt0 = t0c + ktl * 32;
      // ---- build: 768 cells, kp-fast / row-slow, 2 cells per thread ----
#pragma unroll
      for (int cc = 0; cc < 2; ++cc) {
        const int c = tid + cc * 384;
        const int kp = c & 15, row = c >> 4;     // row 0..47
        const int t = kt0 + 2 * kp;              // even
        const int sh = (row < 40) ? (DELAY + (row >> 3)) : 0;
        const int e  = (row < 40) ? (row & 7) : (row - 40);
        const float2 uu = *(const float2*)&ul[t - t0c];   // u0,u1 (b64)
        const float* pr = &panel[e * PSTR];
        const float* pi = &panel[(8 + e) * PSTR];
        float v0r, v0i, v1r, v1i;
        if ((sh & 1) == 0) {                     // even shift: aligned pairs
          int s0l = t - sh - r0;                 // even
          if (s0l < 0) s0l = 0;                  // ch0 clamp (u==0 masks)
          const float2 prp = *(const float2*)&pr[s0l];
          const float2 pip = *(const float2*)&pi[s0l];
          v0r = uu.x * prp.x; v0i = uu.x * pip.x;
          v1r = uu.y * prp.y; v1i = uu.y * pip.y;
        } else {                                 // odd shift: scalar pair
          int s0 = t - sh;     if (s0 < 0) s0 = 0;
          int s1 = t + 1 - sh; if (s1 < 0) s1 = 0;
          v0r = uu.x * pr[s0 - r0]; v0i = uu.x * pi[s0 - r0];
          v1r = uu.y * pr[s1 - r0]; v1i = uu.y * pi[s1 - r0];
        }
        const int idx = row * 40 + 2 * kp;
        {
          const unsigned b0 = __float_as_uint(v0r), b1 = __float_as_uint(v1r);
          *(unsigned*)&tiles[idx] = (b0 >> 16) | (b1 & 0xffff0000u);
          *(unsigned*)&tiles[1920 + idx] =
              bf16rn(v0r - __uint_as_float(b0 & 0xffff0000u)) |
              (bf16rn(v1r - __uint_as_float(b1 & 0xffff0000u)) << 16);
        }
        {
          const unsigned b0 = __float_as_uint(v0i), b1 = __float_as_uint(v1i);
          *(unsigned*)&tiles[3840 + idx] = (b0 >> 16) | (b1 & 0xffff0000u);
          *(unsigned*)&tiles[5760 + idx] =
              bf16rn(v0i - __uint_as_float(b0 & 0xffff0000u)) |
              (bf16rn(v1i - __uint_as_float(b1 & 0xffff0000u)) << 16);
        }
      }
      __syncthreads();
      // ---- MFMA: 12 per wave per K-tile ----
      const s8v crhA = *(const s8v*)&tiles[aoff];
      const s8v crlA = *(const s8v*)&tiles[1920 + aoff];
      const s8v cihA = *(const s8v*)&tiles[3840 + aoff];
      const s8v cilA = *(const s8v*)&tiles[5760 + aoff];
      const s8v crhB = *(const s8v*)&tiles[boff];
      const s8v crlB = *(const s8v*)&tiles[1920 + boff];
      const s8v cihB = *(const s8v*)&tiles[3840 + boff];
      const s8v cilB = *(const s8v*)&tiles[5760 + boff];
      accre  = __builtin_amdgcn_mfma_f32_16x16x32_bf16(crhA, crhB, accre, 0, 0, 0);
      accre  = __builtin_amdgcn_mfma_f32_16x16x32_bf16(crlA, crhB, accre, 0, 0, 0);
      accre  = __builtin_amdgcn_mfma_f32_16x16x32_bf16(crhA, crlB, accre, 0, 0, 0);
      accre  = __builtin_amdgcn_mfma_f32_16x16x32_bf16(cihA, cihB, accre, 0, 0, 0);
      accre  = __builtin_amdgcn_mfma_f32_16x16x32_bf16(cilA, cihB, accre, 0, 0, 0);
      accre  = __builtin_amdgcn_mfma_f32_16x16x32_bf16(cihA, cilB, accre, 0, 0, 0);
      accim1 = __builtin_amdgcn_mfma_f32_16x16x32_bf16(crhA, cihB, accim1, 0, 0, 0);
      accim1 = __builtin_amdgcn_mfma_f32_16x16x32_bf16(crlA, cihB, accim1, 0, 0, 0);
      accim1 = __builtin_amdgcn_mfma_f32_16x16x32_bf16(crhA, cilB, accim1, 0, 0, 0);
      accim2 = __builtin_amdgcn_mfma_f32_16x16x32_bf16(cihA, crhB, accim2, 0, 0, 0);
      accim2 = __builtin_amdgcn_mfma_f32_16x16x32_bf16(cilA, crhB, accim2, 0, 0, 0);
      accim2 = __builtin_amdgcn_mfma_f32_16x16x32_bf16(cihA, crlB, accim2, 0, 0, 0);
      __syncthreads();   // tiles reusable; last kt: panel reads done -> restage ok
    }
  }

  // ---- epilogue: C layout col=lane&15, row=(lane>>4)*4+reg; mirror rt<ct ----
#pragma unroll
  for (int r = 0; r < 4; ++r) {
    const int i = rt * 16 + lk * 4 + r;
    const int j = ct * 16 + lr;
    const float revl = accre[r];
    const float imvl = accim1[r] - accim2[r];
    if (i < 40) {
      float rr = revl;
      if (i == j) rr += 1e-10f;                  // + eps * I on the R diagonal
      Mg[((size_t)bf * 40 + i) * MC + j] = make_float2(rr, imvl);
    }
    if (rt < ct && j < 40) {                     // Hermitian mirror
      Mg[((size_t)bf * 40 + j) * MC + i] = make_float2(revl, -imvl);
    }
  }
}

// ---------------------------------------------------------------------------
// K4 (round-11 optimum): per (b,f) solve (R+eps I) G = b. R is HPD -> real
// pivots -> single v_rcp_f32 (not the complex-reciprocal div chain).
// 128 threads (2 waves); fwd elim 16 row-strips x 8 col-lanes (barrier per k),
// back-subst barrier-free (wave w owns rhs 4w..4w+3, within-wave LDS RAW).
// ---------------------------------------------------------------------------
__global__ __launch_bounds__(128) void k_solve(const float2* __restrict__ Mg,
                                               float2* __restrict__ Gg) {
  const int bf = blockIdx.x;
  __shared__ float ml[40 * RS];
  const int tid = threadIdx.x;
  for (int idx = tid; idx < 40 * MC; idx += 128) {
    const int i = idx / MC, j = idx - i * MC;
    float2 v = Mg[((size_t)bf * 40 + i) * MC + j];
    *(float2*)&ml[i * RS + j * 2] = v;
  }
  __syncthreads();
  const int li = tid >> 3, lj = tid & 7;        // 16 row-strips x 8 col-lanes
  // forward elimination (real-pivot: f = aik * (1/pivot.re))
  for (int k = 0; k < 40; ++k) {
    const float inr = __builtin_amdgcn_rcpf(ml[k * RS + k * 2]);
    for (int i = k + 1 + li; i < 40; i += 16) {
      const float2 aik = *(float2*)&ml[i * RS + k * 2];
      const float fr = aik.x * inr;
      const float fi = aik.y * inr;
      for (int j = k + 1 + lj; j < MC; j += 8) {
        const float2 ak = *(float2*)&ml[k * RS + j * 2];
        float2 ai = *(float2*)&ml[i * RS + j * 2];
        ai.x -= fr * ak.x - fi * ak.y;
        ai.y -= fr * ak.y + fi * ak.x;
        *(float2*)&ml[i * RS + j * 2] = ai;
      }
    }
    __syncthreads();
  }
  // back substitution: wave w -> rhs e = 4w + (lane&3); cc = lane>>2 (16 lanes)
  const int lane = tid & 63, wave = tid >> 6;
  const int e = 4 * wave + (lane & 3), cc = lane >> 2;
  for (int k = 39; k >= 0; --k) {
    float sr = 0.f, si = 0.f;
    for (int j = k + 1 + cc; j < 40; j += 16) {
      const float2 u = *(float2*)&ml[k * RS + j * 2];
      const float2 x = *(float2*)&ml[j * RS + (40 + e) * 2];
      sr += u.x * x.x - u.y * x.y;
      si += u.x * x.y + u.y * x.x;
    }
    sr += __shfl_xor(sr, 4);  si += __shfl_xor(si, 4);
    sr += __shfl_xor(sr, 8);  si += __shfl_xor(si, 8);
    sr += __shfl_xor(sr, 16); si += __shfl_xor(si, 16);
    sr += __shfl_xor(sr, 32); si += __shfl_xor(si, 32);
    if (cc == 0) {
      const float inr = __builtin_amdgcn_rcpf(ml[k * RS + k * 2]);
      const float2 rhs = *(float2*)&ml[k * RS + (40 + e) * 2];
      *(float2*)&ml[k * RS + (40 + e) * 2] =
          make_float2((rhs.x - sr) * inr, (rhs.y - si) * inr);
    }
    asm volatile("" ::: "memory");   // within-wave LDS ordering fence
  }
  __syncthreads();
  for (int idx = tid; idx < 320; idx += 128) {
    const int i = idx >> 3, ee = idx & 7;
    Gg[(size_t)bf * 320 + idx] = *(float2*)&ml[i * RS + (40 + ee) * 2];
  }
}

// ---------------------------------------------------------------------------
// K5 (round-18): chunked + packed tail. E[e,t] = Y[e,t] - sum G[p,d,e]*Y[d,t-3-p]
// 256 threads/block, one block per (b,f). t processed in TWO 256-frame chunks
// (+7-row halo): LDS 23.6 KB => 6 blocks/CU. REVERSE chunk order makes MODE-1
// in-place safe. Packed complex math: gl holds NEGATED G;
// acc += ngr*(yr,yi) + ngi*(-yi,yr).
// MODE 0: write power = mean_e |E|^2.  MODE 1: E -> Yg in place.
// ---------------------------------------------------------------------------
template <int MODE>
__global__ __launch_bounds__(256) void k_tail(float* __restrict__ Yg,
                                              const float2* __restrict__ Gg,
                                              float* __restrict__ pw) {
  const int bf = blockIdx.x;
  __shared__ float yl[TROWS * ROWQ];  // 21040 B (256-chunk + 7 halo)
  __shared__ float gl[640];           // 2560 B: gl[((p*8+d)*8+e)*2] = -G
  const int tid = threadIdx.x;
  for (int idx = tid; idx < 320; idx += 256) {
    float2 g = Gg[(size_t)bf * 320 + idx];
    *(float2*)&gl[idx * 2] = make_float2(-g.x, -g.y);    // negated G
  }
  const float4* ybase4 = (const float4*)(Yg + (size_t)bf * TT * 16);
  float* ybase = Yg + (size_t)bf * TT * 16;

  for (int ch = 1; ch >= 0; --ch) {              // reverse order (in-place safe)
    const int t0c = ch * 256;
    const int r0  = (ch == 0) ? 0 : (t0c - 7);   // panel base (halo below chunk)
    const int nr  = 256 + (t0c - r0);            // 256 (ch0) or 263 (ch1)
    __syncthreads();                             // yl free (prev chunk done)
    for (int fi = tid; fi < nr * 4; fi += 256) {
      const int row = fi >> 2, wq = fi & 3;
      *((float4*)&yl[row * ROWQ + wq * 4]) = ybase4[(size_t)(r0 + row) * 4 + wq];
    }
    __syncthreads();

    const int t = t0c + tid;                     // this thread's frame
    const int lt = t - r0;
    v2f acc[8];
    {
      const float* yr = &yl[lt * ROWQ];
#pragma unroll
      for (int q = 0; q < 8; ++q) {
        const float2 a = *(const float2*)&yr[2 * q];
        acc[q] = (v2f){a.x, a.y};
      }
    }
#pragma unroll 1
    for (int p = 0; p < TAPS; ++p) {
      const int rp = t - DELAY - p;              // <0 only in ch0, tid<8
      const float* yrow = &yl[((rp >= 0 ? rp : 0) - (rp >= 0 ? r0 : 0)) * ROWQ];
      const float m = (rp >= 0) ? 1.0f : 0.0f;
      const float* gp = &gl[p * 128];
#pragma unroll
      for (int d = 0; d < CHN; ++d) {
        const float2 y = *(const float2*)&yrow[2 * d];
        const float yr = m * y.x, yi = m * y.y;
        const v2f yv = (v2f){yr, yi}, ys = (v2f){-yi, yr};
        const float4 g0 = *(const float4*)&gp[d * 16 + 0];   // (ngr,ngi) e0,e1
        const float4 g1 = *(const float4*)&gp[d * 16 + 4];   // e2,e3
        const float4 g2 = *(const float4*)&gp[d * 16 + 8];   // e4,e5
        const float4 g3 = *(const float4*)&gp[d * 16 + 12];  // e6,e7
        const float ngr[8] = {g0.x, g0.z, g1.x, g1.z, g2.x, g2.z, g3.x, g3.z};
        const float ngi[8] = {g0.y, g0.w, g1.y, g1.w, g2.y, g2.w, g3.y, g3.w};
#pragma unroll
        for (int ee = 0; ee < 8; ++ee) {
          const v2f r2 = (v2f){ngr[ee], ngr[ee]};
          const v2f i2 = (v2f){ngi[ee], ngi[ee]};
          acc[ee] = FMA2(r2, yv, FMA2(i2, ys, acc[ee]));
        }
      }
    }
    if (MODE == 0) {
      float ss = 0.f;
#pragma unroll
      for (int q = 0; q < 8; ++q)
        ss += acc[q].x * acc[q].x + acc[q].y * acc[q].y;
      pw[(size_t)bf * TT + t] = ss * (1.0f / CHN);
    } else {
      float4* dst = (float4*)(ybase + (size_t)t * 16);
#pragma unroll
      for (int q = 0; q < 4; ++q)
        dst[q] = make_float4(acc[2 * q].x, acc[2 * q].y,
                             acc[2 * q + 1].x, acc[2 * q + 1].y);
    }
  }
}

// ---------------------------------------------------------------------------
// K6: Yg[b][f][t][c][2] -> out[b][t][c][f][2]
// ---------------------------------------------------------------------------
__global__ void k_unpack(const float* __restrict__ Yg, float* __restrict__ out) {
  const int ft = blockIdx.x, tt = blockIdx.y, b = blockIdx.z;
  const int f0 = ft * 32, t0 = tt * 16;
  __shared__ float ls[32 * 258];
  const int tid = threadIdx.x;
  for (int ff = 0; ff < 32; ++ff) {
    const int fg = f0 + ff;
    if (fg >= FF) break;
    ls[ff * 258 + tid] = Yg[(((size_t)b * FF + fg) * TT + t0) * 16 + tid];
  }
  __syncthreads();
  const int l = tid & 31, r = tid >> 5;
  const int fg = f0 + l;
  if (fg < FF) {
    for (int k = 0; k < 16; ++k) {
      const int task = r + 8 * k;          // 0..127 -> (t,c)
      const int t = task >> 3, c = task & 7;
      const float2 v = *(float2*)&ls[l * 258 + t * 16 + c * 2];
      *(float2*)&out[((((size_t)b * TT + t0 + t) * CHN + c) * FF + fg) * 2] = v;
    }
  }
}

// ---------------------------------------------------------------------------
extern "C" void kernel_launch(void* const* d_in, const int* in_sizes, int n_in,
                              void* d_out, int out_size, void* d_ws, size_t ws_size,
                              hipStream_t stream) {
  const float* re = (const float*)d_in[0];
  const float* im = (const float*)d_in[1];
  float* ws = (float*)d_ws;

  float*  Yg = ws;                                        // NBF*T*16 floats  (67.4 MB)
  float*  pw = Yg + (size_t)NBF * TT * 16;                // NBF*T            (4.2 MB)
  float2* Mg = (float2*)(pw + (size_t)NBF * TT);          // NBF*40*48 cplx   (31.6 MB)
  float2* Gg = Mg + (size_t)NBF * 40 * MC;                // NBF*320 cplx     (5.3 MB)
  float*  out = (float*)d_out;

  const dim3 gridT(9, 32, BB);
  k_pack<<<gridT, 256, 0, stream>>>(re, im, Yg, pw);      // pack + fused power0

  for (int iter = 0; iter < 2; ++iter) {
    k_corr<<<NBF, 384, 0, stream>>>(Yg, pw, Mg);
    k_solve<<<NBF, 128, 0, stream>>>(Mg, Gg);
    if (iter == 0)
      k_tail<0><<<NBF, 256, 0, stream>>>(Yg, Gg, pw);   // -> power for iter 2
    else
      k_tail<1><<<NBF, 256, 0, stream>>>(Yg, Gg, pw);   // -> E in place
  }

  k_unpack<<<gridT, 256, 0, stream>>>(Yg, out);
}

// Round 20
// 418.352 us; speedup vs baseline: 1.0314x; 1.0314x over previous
//
#include <hip/hip_runtime.h>

// Problem constants (B,T,C,F fixed by harness)
constexpr int BB = 8;
constexpr int TT = 512;
constexpr int CHN = 8;
constexpr int FF = 257;
constexpr int TAPS = 5;
constexpr int DELAY = 3;
constexpr int NBF = BB * FF;          // 2056 independent (b,f) systems
constexpr int ROWQ = 20;              // k_tail LDS floats per t-row
constexpr int MC = 48;                // augmented matrix cols (40 R + 8 rhs)
constexpr int RS = 98;                // solver LDS row stride in floats (48*2 + 2 pad)
constexpr int PROWS = 264;            // k_corr chunked panel rows (256 + 7 halo + 1)
constexpr int TROWS = 263;            // k_tail chunked panel rows (256 + 7 halo)

typedef short s8v __attribute__((ext_vector_type(8)));   // bf16x8 MFMA fragment
typedef float f4  __attribute__((ext_vector_type(4)));   // f32x4 accumulator
typedef float v2f __attribute__((ext_vector_type(2)));   // packed f32 pair
#define FMA2(a, b, c) __builtin_elementwise_fma((a), (b), (c))

// ---------------------------------------------------------------------------
// K1: (B,T,C,F) re/im -> Yg[b][f][t][c][2]  (time-contiguous complex layout)
// Also emits power[b][f][t] = mean_c |Y|^2 from the staged tile (fused power0).
// ---------------------------------------------------------------------------
__global__ void k_pack(const float* __restrict__ re, const float* __restrict__ im,
                       float* __restrict__ Yg, float* __restrict__ pw) {
  const int ft = blockIdx.x, tt = blockIdx.y, b = blockIdx.z;
  const int f0 = ft * 32, t0 = tt * 16;
  __shared__ float ls[32 * 258];
  const int tid = threadIdx.x;
  const int l = tid & 31;   // f lane
  const int r = tid >> 5;   // 0..7
  const int f = f0 + l;
  if (f < FF) {
    for (int k = 0; k < 32; ++k) {
      const int task = r + 8 * k;       // 0..255 -> (t,c,ri)
      const int ri = task & 1;
      const int c  = (task >> 1) & 7;
      const int t  = task >> 4;         // 0..15
      const float* src = ri ? im : re;
      const float v = src[(((size_t)b * TT + t0 + t) * CHN + c) * FF + f];
      ls[l * 258 + (t * 16 + c * 2 + ri)] = v;
    }
  }
  __syncthreads();
  for (int ff = 0; ff < 32; ++ff) {
    const int fg = f0 + ff;
    if (fg >= FF) break;
    Yg[(((size_t)b * FF + fg) * TT + t0) * 16 + tid] = ls[ff * 258 + tid];
  }
  // fused initial power: thread (l, r) handles (f=f0+l, t = r, r+8)
  if (f < FF) {
#pragma unroll
    for (int s = 0; s < 2; ++s) {
      const int t = (tid >> 5) + 8 * s;
      const float* row = &ls[l * 258 + t * 16];
      float ss = 0.f;
#pragma unroll
      for (int q = 0; q < 8; ++q) {
        const float2 v = *(const float2*)&row[q * 2];
        ss += v.x * v.x + v.y * v.y;
      }
      pw[((size_t)b * FF + f) * TT + t0 + t] = ss * (1.0f / CHN);
    }
  }
}

// ---------------------------------------------------------------------------
// round-to-nearest f32 -> bf16 bit pattern
// ---------------------------------------------------------------------------
__device__ __forceinline__ unsigned bf16rn(float x) {
  unsigned b = __float_as_uint(x);
  return (b + 0x7fffu + ((b >> 16) & 1u)) >> 16;
}

// ---------------------------------------------------------------------------
// K3 (round-16/18 optimum, 78.5 us): chunked bf16-MFMA corr, INTERLEAVED
// panel (r19 planar variant regressed: conflicts 1.0e7->1.3e7, 78.5->84.5).
// Per (b,f) accumulate M = [R | b] (40x48 complex) via bf16 MFMA.
// sqrt-weight factorization: u[t] = rsqrt(max(p,eps)) (0 for t<7),
//   C[row][t] = u[t]*Y[e][t-3-q] (row<40), u[t]*Y[e][t] (row=40+e),
//   M = C^H C ; Hermitian mirror. 6 waves = upper-tri 16x16 tiles; hi/lo
//   bf16 split (3 MFMA/real product). LDS-tile build, 2 barriers/K-tile.
// K processed in TWO 256-t chunks (panel = 264 rows incl. 7-row tap halo):
// LDS 34.8 KB => 4 blocks/CU.
// ---------------------------------------------------------------------------
__global__ __launch_bounds__(384, 4)
void k_corr(const float* __restrict__ Yg,
            const float* __restrict__ pw,
            float2* __restrict__ Mg) {
  const int bf = blockIdx.x;
  __shared__ float pre[PROWS * 9];               // re panel, slot 8 = u[t]
  __shared__ float pim[PROWS * 9];               // im panel, slot 8 pad
  __shared__ unsigned short tiles[4 * 1920];     // CRH | CRL | CIH | CIL, 48x40
  const int tid = threadIdx.x;

  const int lane = tid & 63, wv = tid >> 6;      // 6 waves
  const int rt = (wv < 3) ? 0 : (wv < 5 ? 1 : 2);
  const int ct = (wv < 3) ? wv : (wv < 5 ? wv - 2 : 2);
  const int lr = lane & 15, lk = lane >> 4;
  const int aoff = (rt * 16 + lr) * 40 + lk * 8;
  const int boff = (ct * 16 + lr) * 40 + lk * 8;

  f4 accre  = {0.f, 0.f, 0.f, 0.f};
  f4 accim1 = {0.f, 0.f, 0.f, 0.f};
  f4 accim2 = {0.f, 0.f, 0.f, 0.f};

  const float4* ybase4 = (const float4*)(Yg + (size_t)bf * TT * 16);

  for (int ch = 0; ch < 2; ++ch) {
    const int t0c = ch * 256;
    const int r0  = (ch == 0) ? 0 : (t0c - 7);   // panel base row (halo below)
    const int nr  = 256 + (t0c - r0);            // 256 (ch0) or 263 (ch1)
    // ---- stage chunk panel rows r0 .. r0+nr-1 ----
    for (int fi = tid; fi < nr * 4; fi += 384) {
      const int row = fi >> 2, q = fi & 3;
      const float4 v = ybase4[(size_t)(r0 + row) * 4 + q];
      pre[row * 9 + 2 * q] = v.x; pre[row * 9 + 2 * q + 1] = v.z;
      pim[row * 9 + 2 * q] = v.y; pim[row * 9 + 2 * q + 1] = v.w;
    }
    for (int t = t0c + tid; t < t0c + 256; t += 384) {
      const float p = pw[(size_t)bf * TT + t];
      pre[(t - r0) * 9 + 8] =
          (t >= DELAY + TAPS - 1) ? rsqrtf(fmaxf(p, 1e-10f)) : 0.0f;
    }
    __syncthreads();                             // panel chunk ready

    for (int ktl = 0; ktl < 8; ++ktl) {
      const int kt0 = t0c + ktl * 32;
      // ---- build: 768 cells, kp-fast / row-slow, 2 cells per thread ----
#pragma unroll
      for (int cc = 0; cc < 2; ++cc) {
        const int c = tid + cc * 384;
        const int kp = c & 15, row = c >> 4;     // row 0..47
        const int t = kt0 + 2 * kp;
        const int sh = (row < 40) ? (DELAY + (row >> 3)) : 0;
        const int e  = (row < 40) ? (row & 7) : (row - 40);
        int s0 = t - sh;     if (s0 < 0) s0 = 0; // clamped reads hit u==0 (ch0)
        int s1 = t + 1 - sh; if (s1 < 0) s1 = 0; // ch1: s >= r0 by halo
        const float u0 = pre[(t - r0) * 9 + 8], u1 = pre[(t + 1 - r0) * 9 + 8];
        const float v0r = u0 * pre[(s0 - r0) * 9 + e];
        const float v0i = u0 * pim[(s0 - r0) * 9 + e];
        const float v1r = u1 * pre[(s1 - r0) * 9 + e];
        const float v1i = u1 * pim[(s1 - r0) * 9 + e];
        const int idx = row * 40 + 2 * kp;
        {
          const unsigned b0 = __float_as_uint(v0r), b1 = __float_as_uint(v1r);
          *(unsigned*)&tiles[idx] = (b0 >> 16) | (b1 & 0xffff0000u);
          *(unsigned*)&tiles[1920 + idx] =
              bf16rn(v0r - __uint_as_float(b0 & 0xffff0000u)) |
              (bf16rn(v1r - __uint_as_float(b1 & 0xffff0000u)) << 16);
        }
        {
          const unsigned b0 = __float_as_uint(v0i), b1 = __float_as_uint(v1i);
          *(unsigned*)&tiles[3840 + idx] = (b0 >> 16) | (b1 & 0xffff0000u);
          *(unsigned*)&tiles[5760 + idx] =
              bf16rn(v0i - __uint_as_float(b0 & 0xffff0000u)) |
              (bf16rn(v1i - __uint_as_float(b1 & 0xffff0000u)) << 16);
        }
      }
      __syncthreads();
      // ---- MFMA: 12 per wave per K-tile ----
      const s8v crhA = *(const s8v*)&tiles[aoff];
      const s8v crlA = *(const s8v*)&tiles[1920 + aoff];
      const s8v cihA = *(const s8v*)&tiles[3840 + aoff];
      const s8v cilA = *(const s8v*)&tiles[5760 + aoff];
      const s8v crhB = *(const s8v*)&tiles[boff];
      const s8v crlB = *(const s8v*)&tiles[1920 + boff];
      const s8v cihB = *(const s8v*)&tiles[3840 + boff];
      const s8v cilB = *(const s8v*)&tiles[5760 + boff];
      accre  = __builtin_amdgcn_mfma_f32_16x16x32_bf16(crhA, crhB, accre, 0, 0, 0);
      accre  = __builtin_amdgcn_mfma_f32_16x16x32_bf16(crlA, crhB, accre, 0, 0, 0);
      accre  = __builtin_amdgcn_mfma_f32_16x16x32_bf16(crhA, crlB, accre, 0, 0, 0);
      accre  = __builtin_amdgcn_mfma_f32_16x16x32_bf16(cihA, cihB, accre, 0, 0, 0);
      accre  = __builtin_amdgcn_mfma_f32_16x16x32_bf16(cilA, cihB, accre, 0, 0, 0);
      accre  = __builtin_amdgcn_mfma_f32_16x16x32_bf16(cihA, cilB, accre, 0, 0, 0);
      accim1 = __builtin_amdgcn_mfma_f32_16x16x32_bf16(crhA, cihB, accim1, 0, 0, 0);
      accim1 = __builtin_amdgcn_mfma_f32_16x16x32_bf16(crlA, cihB, accim1, 0, 0, 0);
      accim1 = __builtin_amdgcn_mfma_f32_16x16x32_bf16(crhA, cilB, accim1, 0, 0, 0);
      accim2 = __builtin_amdgcn_mfma_f32_16x16x32_bf16(cihA, crhB, accim2, 0, 0, 0);
      accim2 = __builtin_amdgcn_mfma_f32_16x16x32_bf16(cilA, crhB, accim2, 0, 0, 0);
      accim2 = __builtin_amdgcn_mfma_f32_16x16x32_bf16(cihA, crlB, accim2, 0, 0, 0);
      __syncthreads();   // tiles reusable; last kt: panel reads done -> restage ok
    }
  }

  // ---- epilogue: C layout col=lane&15, row=(lane>>4)*4+reg; mirror rt<ct ----
#pragma unroll
  for (int r = 0; r < 4; ++r) {
    const int i = rt * 16 + lk * 4 + r;
    const int j = ct * 16 + lr;
    const float revl = accre[r];
    const float imvl = accim1[r] - accim2[r];
    if (i < 40) {
      float rr = revl;
      if (i == j) rr += 1e-10f;                  // + eps * I on the R diagonal
      Mg[((size_t)bf * 40 + i) * MC + j] = make_float2(rr, imvl);
    }
    if (rt < ct && j < 40) {                     // Hermitian mirror
      Mg[((size_t)bf * 40 + j) * MC + i] = make_float2(revl, -imvl);
    }
  }
}

// ---------------------------------------------------------------------------
// K4 (round-11 optimum): per (b,f) solve (R+eps I) G = b. R is HPD -> real
// pivots -> single v_rcp_f32 (not the complex-reciprocal div chain).
// 128 threads (2 waves); fwd elim 16 row-strips x 8 col-lanes (barrier per k),
// back-subst barrier-free (wave w owns rhs 4w..4w+3, within-wave LDS RAW).
// ---------------------------------------------------------------------------
__global__ __launch_bounds__(128) void k_solve(const float2* __restrict__ Mg,
                                               float2* __restrict__ Gg) {
  const int bf = blockIdx.x;
  __shared__ float ml[40 * RS];
  const int tid = threadIdx.x;
  for (int idx = tid; idx < 40 * MC; idx += 128) {
    const int i = idx / MC, j = idx - i * MC;
    float2 v = Mg[((size_t)bf * 40 + i) * MC + j];
    *(float2*)&ml[i * RS + j * 2] = v;
  }
  __syncthreads();
  const int li = tid >> 3, lj = tid & 7;        // 16 row-strips x 8 col-lanes
  // forward elimination (real-pivot: f = aik * (1/pivot.re))
  for (int k = 0; k < 40; ++k) {
    const float inr = __builtin_amdgcn_rcpf(ml[k * RS + k * 2]);
    for (int i = k + 1 + li; i < 40; i += 16) {
      const float2 aik = *(float2*)&ml[i * RS + k * 2];
      const float fr = aik.x * inr;
      const float fi = aik.y * inr;
      for (int j = k + 1 + lj; j < MC; j += 8) {
        const float2 ak = *(float2*)&ml[k * RS + j * 2];
        float2 ai = *(float2*)&ml[i * RS + j * 2];
        ai.x -= fr * ak.x - fi * ak.y;
        ai.y -= fr * ak.y + fi * ak.x;
        *(float2*)&ml[i * RS + j * 2] = ai;
      }
    }
    __syncthreads();
  }
  // back substitution: wave w -> rhs e = 4w + (lane&3); cc = lane>>2 (16 lanes)
  const int lane = tid & 63, wave = tid >> 6;
  const int e = 4 * wave + (lane & 3), cc = lane >> 2;
  for (int k = 39; k >= 0; --k) {
    float sr = 0.f, si = 0.f;
    for (int j = k + 1 + cc; j < 40; j += 16) {
      const float2 u = *(float2*)&ml[k * RS + j * 2];
      const float2 x = *(float2*)&ml[j * RS + (40 + e) * 2];
      sr += u.x * x.x - u.y * x.y;
      si += u.x * x.y + u.y * x.x;
    }
    sr += __shfl_xor(sr, 4);  si += __shfl_xor(si, 4);
    sr += __shfl_xor(sr, 8);  si += __shfl_xor(si, 8);
    sr += __shfl_xor(sr, 16); si += __shfl_xor(si, 16);
    sr += __shfl_xor(sr, 32); si += __shfl_xor(si, 32);
    if (cc == 0) {
      const float inr = __builtin_amdgcn_rcpf(ml[k * RS + k * 2]);
      const float2 rhs = *(float2*)&ml[k * RS + (40 + e) * 2];
      *(float2*)&ml[k * RS + (40 + e) * 2] =
          make_float2((rhs.x - sr) * inr, (rhs.y - si) * inr);
    }
    asm volatile("" ::: "memory");   // within-wave LDS ordering fence
  }
  __syncthreads();
  for (int idx = tid; idx < 320; idx += 128) {
    const int i = idx >> 3, ee = idx & 7;
    Gg[(size_t)bf * 320 + idx] = *(float2*)&ml[i * RS + (40 + ee) * 2];
  }
}

// ---------------------------------------------------------------------------
// K5 (round-18): chunked + packed tail. E[e,t] = Y[e,t] - sum G[p,d,e]*Y[d,t-3-p]
// 256 threads/block, one block per (b,f). t processed in TWO 256-frame chunks
// (+7-row halo): LDS 23.6 KB => 6 blocks/CU. REVERSE chunk order makes MODE-1
// in-place safe. Packed complex math: gl holds NEGATED G;
// acc += ngr*(yr,yi) + ngi*(-yi,yr).
// MODE 0: write power = mean_e |E|^2.  MODE 1: E -> Yg in place.
// ---------------------------------------------------------------------------
template <int MODE>
__global__ __launch_bounds__(256) void k_tail(float* __restrict__ Yg,
                                              const float2* __restrict__ Gg,
                                              float* __restrict__ pw) {
  const int bf = blockIdx.x;
  __shared__ float yl[TROWS * ROWQ];  // 21040 B (256-chunk + 7 halo)
  __shared__ float gl[640];           // 2560 B: gl[((p*8+d)*8+e)*2] = -G
  const int tid = threadIdx.x;
  for (int idx = tid; idx < 320; idx += 256) {
    float2 g = Gg[(size_t)bf * 320 + idx];
    *(float2*)&gl[idx * 2] = make_float2(-g.x, -g.y);    // negated G
  }
  const float4* ybase4 = (const float4*)(Yg + (size_t)bf * TT * 16);
  float* ybase = Yg + (size_t)bf * TT * 16;

  for (int ch = 1; ch >= 0; --ch) {              // reverse order (in-place safe)
    const int t0c = ch * 256;
    const int r0  = (ch == 0) ? 0 : (t0c - 7);   // panel base (halo below chunk)
    const int nr  = 256 + (t0c - r0);            // 256 (ch0) or 263 (ch1)
    __syncthreads();                             // yl free (prev chunk done)
    for (int fi = tid; fi < nr * 4; fi += 256) {
      const int row = fi >> 2, wq = fi & 3;
      *((float4*)&yl[row * ROWQ + wq * 4]) = ybase4[(size_t)(r0 + row) * 4 + wq];
    }
    __syncthreads();

    const int t = t0c + tid;                     // this thread's frame
    const int lt = t - r0;
    v2f acc[8];
    {
      const float* yr = &yl[lt * ROWQ];
#pragma unroll
      for (int q = 0; q < 8; ++q) {
        const float2 a = *(const float2*)&yr[2 * q];
        acc[q] = (v2f){a.x, a.y};
      }
    }
#pragma unroll 1
    for (int p = 0; p < TAPS; ++p) {
      const int rp = t - DELAY - p;              // <0 only in ch0, tid<8
      const float* yrow = &yl[((rp >= 0 ? rp : 0) - (rp >= 0 ? r0 : 0)) * ROWQ];
      const float m = (rp >= 0) ? 1.0f : 0.0f;
      const float* gp = &gl[p * 128];
#pragma unroll
      for (int d = 0; d < CHN; ++d) {
        const float2 y = *(const float2*)&yrow[2 * d];
        const float yr = m * y.x, yi = m * y.y;
        const v2f yv = (v2f){yr, yi}, ys = (v2f){-yi, yr};
        const float4 g0 = *(const float4*)&gp[d * 16 + 0];   // (ngr,ngi) e0,e1
        const float4 g1 = *(const float4*)&gp[d * 16 + 4];   // e2,e3
        const float4 g2 = *(const float4*)&gp[d * 16 + 8];   // e4,e5
        const float4 g3 = *(const float4*)&gp[d * 16 + 12];  // e6,e7
        const float ngr[8] = {g0.x, g0.z, g1.x, g1.z, g2.x, g2.z, g3.x, g3.z};
        const float ngi[8] = {g0.y, g0.w, g1.y, g1.w, g2.y, g2.w, g3.y, g3.w};
#pragma unroll
        for (int ee = 0; ee < 8; ++ee) {
          const v2f r2 = (v2f){ngr[ee], ngr[ee]};
          const v2f i2 = (v2f){ngi[ee], ngi[ee]};
          acc[ee] = FMA2(r2, yv, FMA2(i2, ys, acc[ee]));
        }
      }
    }
    if (MODE == 0) {
      float ss = 0.f;
#pragma unroll
      for (int q = 0; q < 8; ++q)
        ss += acc[q].x * acc[q].x + acc[q].y * acc[q].y;
      pw[(size_t)bf * TT + t] = ss * (1.0f / CHN);
    } else {
      float4* dst = (float4*)(ybase + (size_t)t * 16);
#pragma unroll
      for (int q = 0; q < 4; ++q)
        dst[q] = make_float4(acc[2 * q].x, acc[2 * q].y,
                             acc[2 * q + 1].x, acc[2 * q + 1].y);
    }
  }
}

// ---------------------------------------------------------------------------
// K6: Yg[b][f][t][c][2] -> out[b][t][c][f][2]
// ---------------------------------------------------------------------------
__global__ void k_unpack(const float* __restrict__ Yg, float* __restrict__ out) {
  const int ft = blockIdx.x, tt = blockIdx.y, b = blockIdx.z;
  const int f0 = ft * 32, t0 = tt * 16;
  __shared__ float ls[32 * 258];
  const int tid = threadIdx.x;
  for (int ff = 0; ff < 32; ++ff) {
    const int fg = f0 + ff;
    if (fg >= FF) break;
    ls[ff * 258 + tid] = Yg[(((size_t)b * FF + fg) * TT + t0) * 16 + tid];
  }
  __syncthreads();
  const int l = tid & 31, r = tid >> 5;
  const int fg = f0 + l;
  if (fg < FF) {
    for (int k = 0; k < 16; ++k) {
      const int task = r + 8 * k;          // 0..127 -> (t,c)
      const int t = task >> 3, c = task & 7;
      const float2 v = *(float2*)&ls[l * 258 + t * 16 + c * 2];
      *(float2*)&out[((((size_t)b * TT + t0 + t) * CHN + c) * FF + fg) * 2] = v;
    }
  }
}

// ---------------------------------------------------------------------------
extern "C" void kernel_launch(void* const* d_in, const int* in_sizes, int n_in,
                              void* d_out, int out_size, void* d_ws, size_t ws_size,
                              hipStream_t stream) {
  const float* re = (const float*)d_in[0];
  const float* im = (const float*)d_in[1];
  float* ws = (float*)d_ws;

  float*  Yg = ws;                                        // NBF*T*16 floats  (67.4 MB)
  float*  pw = Yg + (size_t)NBF * TT * 16;                // NBF*T            (4.2 MB)
  float2* Mg = (float2*)(pw + (size_t)NBF * TT);          // NBF*40*48 cplx   (31.6 MB)
  float2* Gg = Mg + (size_t)NBF * 40 * MC;                // NBF*320 cplx     (5.3 MB)
  float*  out = (float*)d_out;

  const dim3 gridT(9, 32, BB);
  k_pack<<<gridT, 256, 0, stream>>>(re, im, Yg, pw);      // pack + fused power0

  for (int iter = 0; iter < 2; ++iter) {
    k_corr<<<NBF, 384, 0, stream>>>(Yg, pw, Mg);
    k_solve<<<NBF, 128, 0, stream>>>(Mg, Gg);
    if (iter == 0)
      k_tail<0><<<NBF, 256, 0, stream>>>(Yg, Gg, pw);   // -> power for iter 2
    else
      k_tail<1><<<NBF, 256, 0, stream>>>(Yg, Gg, pw);   // -> E in place
  }

  k_unpack<<<gridT, 256, 0, stream>>>(Yg, out);
}